// Round 3
// baseline (637.768 us; speedup 1.0000x reference)
//
#include <hip/hip_runtime.h>
#include <hip/hip_cooperative_groups.h>

namespace cg = cooperative_groups;

#define NN   2048
#define ROWS 4096           // B*N
#define NBLK 256
#define NTHR 512
#define RPB  16             // rows per block
// LDS: dF[16][2048] + aS[2][2048] + qC0[2048] + rstage[16]
#define SMEM_FLOATS (RPB*NN + 2*NN + NN + 16)
#define SMEM_BYTES  (SMEM_FLOATS*4)

__device__ __forceinline__ float fsig(float x) {
    float e = __expf(-x);
    return __builtin_amdgcn_rcpf(1.0f + e);
}

__global__ void kfused(const float* __restrict__ S, const float* __restrict__ C,
                       const float4* __restrict__ F, const float* __restrict__ w,
                       float* __restrict__ outS, float* __restrict__ outC,
                       float4* __restrict__ outF,
                       float* __restrict__ rb, float* __restrict__ cb)
{
    cg::grid_group grid = cg::this_grid();
    extern __shared__ float smem[];
    float* dF     = smem;                 // [RPB][NN]
    float* aSb    = smem + RPB*NN;        // [2][NN]   ping-pong aS
    float* qC0    = aSb + 2*NN;           // [NN]
    float* rstage = qC0 + NN;             // [RPB]

    const int tid  = threadIdx.x;
    const int blk  = blockIdx.x;
    const int b    = blk >> 7;            // batch (128 blocks per batch)
    const int bloc = blk & 127;
    const int row0 = blk * RPB;           // global row base
    const int base = b * NN;              // batch offset into state arrays
    const float w0 = w[0], w1 = w[1];
    const int lane = tid & 63;
    const int y0   = 4 * tid;             // this thread's 4 columns (batch-local)

    // ---------- init ----------
    if (tid < 48) cb[(tid >> 4) * ROWS + row0 + (tid & 15)] = 0.0f;  // zero all 3 c slices
    if (tid < RPB) rstage[tid] = 0.0f;
    for (int i = tid; i < NN; i += NTHR) {
        int g = base + i;
        float2 sv = *(const float2*)&S[2*g];
        float2 cv = *(const float2*)&C[2*g];
        aSb[i] = fsig(sv.y - sv.x);       // aS_0 in buf0
        qC0[i] = fsig(cv.x - cv.y);       // qC0_0
    }
    for (int u = tid; u < RPB*(NN/2); u += NTHR) {   // 16384 float4 loads / block
        int ir = u >> 10;
        int j  = u & 1023;
        float4 f = F[(size_t)(row0 + ir) * (NN/2) + j];
        *(float2*)&dF[ir*NN + 2*j] = make_float2(f.y - f.x, f.w - f.z);
    }
    __threadfence();
    grid.sync();

    // ---------- 5 steps ----------
    for (int k = 0; k < 5; k++) {
        float* aScur  = aSb + (k & 1) * NN;
        float* aSprev = aSb + ((k & 1) ^ 1) * NN;
        if (k > 0) {
            const float* rprev = rb + ((k - 1) & 1) * ROWS;
            const float* cprev = cb + ((k - 1) % 3) * ROWS;
            for (int i = tid; i < NN; i += NTHR) {
                int g = base + i;
                float2 sv = *(const float2*)&S[2*g];
                float2 cv = *(const float2*)&C[2*g];
                float ap = aSprev[i];
                float s0 = sv.x + w0 * qC0[i] + w1 * rprev[g];
                float s1 = sv.y + w1 * cprev[g];
                aScur[i] = fsig(s1 - s0);
                qC0[i]   = fsig(cv.x - cv.y - w0 * ap);
            }
            // zero the c buffer pass k+1 will use (safe: last read in step k-1)
            if (tid < RPB) cb[((k + 1) % 3) * ROWS + row0 + tid] = 0.0f;
        }
        __syncthreads();

        // pass k over LDS dF shard
        const float wq0 = 1.0f - aScur[y0],     wq1 = 1.0f - aScur[y0 + 1],
                    wq2 = 1.0f - aScur[y0 + 2], wq3 = 1.0f - aScur[y0 + 3];
        float bp0 = 0.f, bp1 = 0.f, bp2 = 0.f, bp3 = 0.f;
        if (k > 0) {
            bp0 = 1.0f - aSprev[y0];     bp1 = 1.0f - aSprev[y0 + 1];
            bp2 = 1.0f - aSprev[y0 + 2]; bp3 = 1.0f - aSprev[y0 + 3];
        }
        float cacc0 = 0.f, cacc1 = 0.f, cacc2 = 0.f, cacc3 = 0.f;
#pragma unroll 4
        for (int ir = 0; ir < RPB; ir++) {
            const int xl = bloc * RPB + ir;            // batch-local row index
            const float a_c = aScur[xl];
            const float m1  = (k > 0) ? w1 * aSprev[xl] : 0.0f;
            float4 d = *(float4*)&dF[ir * NN + y0];
            float s0 = fsig(d.x - m1 * bp0);
            float s1 = fsig(d.y - m1 * bp1);
            float s2 = fsig(d.z - m1 * bp2);
            float s3 = fsig(d.w - m1 * bp3);
            cacc0 += s0 * a_c; cacc1 += s1 * a_c;
            cacc2 += s2 * a_c; cacc3 += s3 * a_c;
            float ra = s0 * wq0 + s1 * wq1 + s2 * wq2 + s3 * wq3;
#pragma unroll
            for (int off = 32; off > 0; off >>= 1) ra += __shfl_down(ra, off);
            if (lane == 0) atomicAdd(&rstage[ir], ra);
            if (k == 4) {   // fused out_F write (re-read F: L3-resident)
                const float mw = w1 * a_c;
                size_t fo = (size_t)(row0 + ir) * (NN/2) + 2 * tid;
                float4 fa = F[fo], fb = F[fo + 1];
                fa.x += mw * wq0; fa.z += mw * wq1;
                fb.x += mw * wq2; fb.z += mw * wq3;
                outF[fo] = fa; outF[fo + 1] = fb;
            }
        }
        float* ccur = cb + (k % 3) * ROWS;
        atomicAdd(&ccur[base + y0],     cacc0);
        atomicAdd(&ccur[base + y0 + 1], cacc1);
        atomicAdd(&ccur[base + y0 + 2], cacc2);
        atomicAdd(&ccur[base + y0 + 3], cacc3);
        __syncthreads();                  // rstage atomics done
        if (tid < RPB) {
            rb[(k & 1) * ROWS + row0 + tid] = rstage[tid];
            rstage[tid] = 0.0f;
        }
        __threadfence();
        grid.sync();
    }

    // ---------- epilogue: outS, outC for own 16 rows ----------
    if (tid < RPB) {
        int g  = row0 + tid;
        int il = bloc * RPB + tid;        // batch-local index
        float2 sv = *(const float2*)&S[2*g];
        float2 cv = *(const float2*)&C[2*g];
        float rv = rb[0 * ROWS + g];      // pass 4 wrote rb buf 0
        float cc = cb[(4 % 3) * ROWS + g];
        float a4 = aSb[(4 & 1) * NN + il];
        outS[2*g]     = sv.x + w0 * qC0[il] + w1 * rv;
        outS[2*g + 1] = sv.y + w1 * cc;
        outC[2*g]     = cv.x;
        outC[2*g + 1] = cv.y + w0 * a4;
    }
}

extern "C" void kernel_launch(void* const* d_in, const int* in_sizes, int n_in,
                              void* d_out, int out_size, void* d_ws, size_t ws_size,
                              hipStream_t stream)
{
    const float* S = (const float*)d_in[0];
    const float* C = (const float*)d_in[1];
    const float4* F4 = (const float4*)d_in[2];
    const float* w = (const float*)d_in[3];
    float* out = (float*)d_out;
    float* ws  = (float*)d_ws;

    float* outS = out;
    float* outC = out + 2 * ROWS;              // 8192
    float4* outF = (float4*)(out + 4 * ROWS);

    float* rb = ws;                 // 2 * 4096
    float* cb = ws + 2 * ROWS;      // 3 * 4096   (total 80 KB)

    static bool attr_set = false;
    if (!attr_set) {
        hipFuncSetAttribute((const void*)kfused,
                            hipFuncAttributeMaxDynamicSharedMemorySize, SMEM_BYTES);
        attr_set = true;
    }

    void* args[] = { (void*)&S, (void*)&C, (void*)&F4, (void*)&w,
                     (void*)&outS, (void*)&outC, (void*)&outF,
                     (void*)&rb, (void*)&cb };
    hipLaunchCooperativeKernel((const void*)kfused, dim3(NBLK), dim3(NTHR),
                               args, SMEM_BYTES, stream);
}

// Round 4
// 207.034 us; speedup vs baseline: 3.0805x; 3.0805x over previous
//
#include <hip/hip_runtime.h>

#define BB 2
#define NN 2048
#define ROWS (BB*NN)   // 4096
#define RPB 16         // rows per block in big pass
#define CSPLIT 4       // column splits (each block: 256 float4 cols)
#define NCSL 8         // c accumulator slices (chain depth 128/8 = 16)
#define NRSL 2         // r accumulator slices (chain depth 16/2 = 8)

__device__ __forceinline__ float fsig(float x) {
    float e = __expf(-x);
    return __builtin_amdgcn_rcpf(1.0f + e);
}

// Per-step state kernel: sums r/c slices, computes aS_t, qC0_t, re-zeroes slices.
__global__ void ksmall(const float* __restrict__ S, const float* __restrict__ C,
                       const float* __restrict__ w,
                       float* __restrict__ rpart, float* __restrict__ cpart,
                       const float* __restrict__ aS_prev, float* __restrict__ aS_cur,
                       float* __restrict__ qC0, int first)
{
    int idx = blockIdx.x * blockDim.x + threadIdx.x;
    if (idx >= ROWS) return;
    float w0 = w[0], w1 = w[1];
    float2 sv = ((const float2*)S)[idx];
    float2 cv = ((const float2*)C)[idx];
    float aS, qc;
    if (first) {
        aS = fsig(sv.y - sv.x);
        qc = fsig(cv.x - cv.y);
#pragma unroll
        for (int s = 0; s < NRSL; s++) rpart[s*ROWS + idx] = 0.0f;
#pragma unroll
        for (int s = 0; s < NCSL; s++) cpart[s*ROWS + idx] = 0.0f;
    } else {
        float rs = 0.0f;
#pragma unroll
        for (int s = 0; s < NRSL; s++) { rs += rpart[s*ROWS + idx]; rpart[s*ROWS + idx] = 0.0f; }
        float cs = 0.0f;
#pragma unroll
        for (int s = 0; s < NCSL; s++) { cs += cpart[s*ROWS + idx]; cpart[s*ROWS + idx] = 0.0f; }
        float ap  = aS_prev[idx];
        float qcp = qC0[idx];
        float s0 = sv.x + w0*qcp + w1*rs;
        float s1 = sv.y + w1*cs;
        aS = fsig(s1 - s0);
        qc = fsig(cv.x - cv.y - w0*ap);
    }
    aS_cur[idx] = aS;
    qC0[idx]    = qc;
}

// Big pass over logits_F. Sliced-accumulator atomics; wave-level r reduction.
// MODE 0: first step (m=0), MODE 1: middle, MODE 2: final (also writes out_F).
template<int MODE>
__global__ __launch_bounds__(256) void kbig(
    const float4* __restrict__ F,
    const float* __restrict__ aS_cur, const float* __restrict__ aS_prev,
    const float* __restrict__ w,
    float* __restrict__ rpart, float* __restrict__ cpart,
    float4* __restrict__ outF)
{
    const int tid  = threadIdx.x;
    const int sx   = blockIdx.x;
    const int by   = blockIdx.y;
    const int j    = sx * 256 + tid;             // float4 column in [0, NN/2)
    const int row0 = by * RPB;
    const int b    = row0 >> 11;                 // 2048 rows per batch
    const int lane = tid & 63;
    const float w1 = w[1];

    float* rdst = rpart + (sx & (NRSL-1)) * ROWS;
    float* cdst = cpart + (by & (NCSL-1)) * ROWS;

    const float wq0 = 1.0f - aS_cur[b*NN + 2*j];
    const float wq1 = 1.0f - aS_cur[b*NN + 2*j + 1];
    float bp0 = 0.0f, bp1 = 0.0f;
    if (MODE != 0) {
        bp0 = 1.0f - aS_prev[b*NN + 2*j];
        bp1 = 1.0f - aS_prev[b*NN + 2*j + 1];
    }

    float c0 = 0.0f, c1 = 0.0f;

#pragma unroll 4
    for (int i = 0; i < RPB; i++) {
        const int row = row0 + i;
        const int x   = row & (NN - 1);
        const float a_c = aS_cur[b*NN + x];
        float m1 = 0.0f;
        if (MODE != 0) m1 = w1 * aS_prev[b*NN + x];

        const float4 f = F[(size_t)row * (NN/2) + j];
        const float d0 = f.y - f.x;
        const float d1 = f.w - f.z;
        float s0, s1;
        if (MODE == 0) { s0 = fsig(d0); s1 = fsig(d1); }
        else           { s0 = fsig(d0 - m1*bp0); s1 = fsig(d1 - m1*bp1); }

        c0 += s0 * a_c;
        c1 += s1 * a_c;

        if (MODE == 2) {
            const float mw = w1 * a_c;
            float4 o;
            o.x = f.x + mw*wq0;
            o.y = f.y;
            o.z = f.z + mw*wq1;
            o.w = f.w;
            outF[(size_t)row * (NN/2) + j] = o;
        }

        // r partial for this row: wave reduce, one far-atomic per wave
        // (chain depth per address: 4 waves x CSPLIT/NRSL blocks = 8)
        float ra = s0*wq0 + s1*wq1;
#pragma unroll
        for (int off = 32; off > 0; off >>= 1) ra += __shfl_down(ra, off);
        if (lane == 0) atomicAdd(&rdst[row], ra);
    }

    // chain depth per address: 128 row-groups / NCSL = 16
    atomicAdd(&cdst[b*NN + 2*j],     c0);
    atomicAdd(&cdst[b*NN + 2*j + 1], c1);
}

// Final epilogue: out_S, out_C from (qC0_4, r_4, c_4, aS_4). Sums slices.
__global__ void kfin(const float* __restrict__ S, const float* __restrict__ C,
                     const float* __restrict__ w,
                     const float* __restrict__ rpart, const float* __restrict__ cpart,
                     const float* __restrict__ aS4, const float* __restrict__ qC0,
                     float* __restrict__ outS, float* __restrict__ outC)
{
    int idx = blockIdx.x * blockDim.x + threadIdx.x;
    if (idx >= ROWS) return;
    float w0 = w[0], w1 = w[1];
    float rs = 0.0f;
#pragma unroll
    for (int s = 0; s < NRSL; s++) rs += rpart[s*ROWS + idx];
    float cs = 0.0f;
#pragma unroll
    for (int s = 0; s < NCSL; s++) cs += cpart[s*ROWS + idx];
    float2 sv = ((const float2*)S)[idx];
    float2 cv = ((const float2*)C)[idx];
    float2 os, oc;
    os.x = sv.x + w0*qC0[idx] + w1*rs;
    os.y = sv.y + w1*cs;
    oc.x = cv.x;
    oc.y = cv.y + w0*aS4[idx];
    ((float2*)outS)[idx] = os;
    ((float2*)outC)[idx] = oc;
}

extern "C" void kernel_launch(void* const* d_in, const int* in_sizes, int n_in,
                              void* d_out, int out_size, void* d_ws, size_t ws_size,
                              hipStream_t stream)
{
    const float* S = (const float*)d_in[0];
    const float* C = (const float*)d_in[1];
    const float* F = (const float*)d_in[2];
    const float* w = (const float*)d_in[3];
    float* out = (float*)d_out;
    float* ws  = (float*)d_ws;

    float* rpart = ws;                        // NRSL * 4096
    float* cpart = ws + NRSL*ROWS;            // NCSL * 4096
    float* aSA   = ws + (NRSL+NCSL)*ROWS;     // 4096
    float* aSB   = aSA + ROWS;                // 4096
    float* qC0   = aSB + ROWS;                // 4096   (total 13*16KB = 208 KB)

    const float4* F4 = (const float4*)F;
    float* outS = out;
    float* outC = out + 2*ROWS;               // 8192
    float4* outF = (float4*)(out + 4*ROWS);

    dim3 gs(ROWS/256), bs(256);
    dim3 gb(CSPLIT, ROWS/RPB), bbk(256);

    // t=0 : cur = aSA
    ksmall<<<gs, bs, 0, stream>>>(S, C, w, rpart, cpart, aSB, aSA, qC0, 1);
    kbig<0><<<gb, bbk, 0, stream>>>(F4, aSA, aSB, w, rpart, cpart, nullptr);
    // t=1 : prev = aSA, cur = aSB
    ksmall<<<gs, bs, 0, stream>>>(S, C, w, rpart, cpart, aSA, aSB, qC0, 0);
    kbig<1><<<gb, bbk, 0, stream>>>(F4, aSB, aSA, w, rpart, cpart, nullptr);
    // t=2 : prev = aSB, cur = aSA
    ksmall<<<gs, bs, 0, stream>>>(S, C, w, rpart, cpart, aSB, aSA, qC0, 0);
    kbig<1><<<gb, bbk, 0, stream>>>(F4, aSA, aSB, w, rpart, cpart, nullptr);
    // t=3 : prev = aSA, cur = aSB
    ksmall<<<gs, bs, 0, stream>>>(S, C, w, rpart, cpart, aSA, aSB, qC0, 0);
    kbig<1><<<gb, bbk, 0, stream>>>(F4, aSB, aSA, w, rpart, cpart, nullptr);
    // t=4 : prev = aSB, cur = aSA ; fused out_F write
    ksmall<<<gs, bs, 0, stream>>>(S, C, w, rpart, cpart, aSB, aSA, qC0, 0);
    kbig<2><<<gb, bbk, 0, stream>>>(F4, aSA, aSB, w, rpart, cpart, outF);
    // epilogue: out_S, out_C
    kfin<<<gs, bs, 0, stream>>>(S, C, w, rpart, cpart, aSA, qC0, outS, outC);
}

// Round 5
// 186.468 us; speedup vs baseline: 3.4203x; 1.1103x over previous
//
#include <hip/hip_runtime.h>

#define NN   2048
#define ROWS 4096          // B*N
#define RPB  16            // rows per block
#define CSPLIT 4           // column splits; block covers 256 float4 cols
#define NBY  (ROWS/RPB)    // 256
#define NCSL 8             // c-accumulator slices
#define PSTR 257           // LDS partial stride

__device__ __forceinline__ float fsig(float x) {
    float e = __expf(-x);
    return __builtin_amdgcn_rcpf(1.0f + e);
}

// Pass T over F with fused state computation.
// Prologue: aS_T (cur) + aS_{T-1} (prev) for this block's 512 y-cols + 16 x-rows.
// Main: r_T[x] = sum_y sig(dF - m)*(1-aS_T[y]) ; c_T[y] += sum_x sig(dF - m)*aS_T[x]
//       m = w1*aS_{T-1}[x]*(1-aS_{T-1}[y]).  T==4 also writes out_F.
template<int T>
__global__ __launch_bounds__(256) void kbig(
    const float4* __restrict__ F,
    const float2* __restrict__ S2, const float2* __restrict__ C2,
    const float* __restrict__ w,
    const float* __restrict__ rprev, const float* __restrict__ cprev,
    const float* __restrict__ aSm1, const float* __restrict__ aSm2,
    float* __restrict__ rout, float* __restrict__ cout,
    float* __restrict__ czero, float* __restrict__ aSout,
    float4* __restrict__ outF)
{
    __shared__ float sCur[528];
    __shared__ float sPrev[528];
    __shared__ float part[16 * PSTR];

    const int tid  = threadIdx.x;
    const int sx   = blockIdx.x;          // 0..3  column split
    const int by   = blockIdx.y;          // 0..255 row group
    const int row0 = by * RPB;
    const int b    = by >> 7;             // batch
    const int bloc = by & 127;            // row group within batch
    const int base = b * NN;
    const float w0 = w[0], w1 = w[1];

    // zero the c buffer pass T+1 will accumulate into (exclusive coverage)
    if (T < 4 && sx == 1) {
        int zi = by * 256 + tid;
        if (zi < NCSL * ROWS) czero[zi] = 0.0f;
    }

    // ---- prologue: state for the 528 indices this block touches ----
    for (int idx = tid; idx < 528; idx += 256) {
        int il = (idx < 512) ? (sx * 512 + idx) : (bloc * RPB + idx - 512);
        int g  = base + il;
        float2 sv = S2[g];
        float a0 = fsig(sv.y - sv.x);          // aS_0, always cheap
        float cur, prev;
        if (T == 0) {
            cur = a0; prev = 0.0f;
        } else {
            float2 cv = C2[g];
            float rs = rprev[0*ROWS+g] + rprev[1*ROWS+g]
                     + rprev[2*ROWS+g] + rprev[3*ROWS+g];
            float cs = 0.0f;
#pragma unroll
            for (int s = 0; s < NCSL; s++) cs += cprev[s*ROWS + g];
            float qc;                            // qC0_{T-1}
            if (T == 1)      qc = fsig(cv.x - cv.y);
            else if (T == 2) qc = fsig(cv.x - cv.y - w0 * a0);
            else             qc = fsig(cv.x - cv.y - w0 * aSm2[g]);
            cur  = fsig((sv.y + w1*cs) - (sv.x + w0*qc + w1*rs));
            prev = (T == 1) ? a0 : aSm1[g];
        }
        sCur[idx]  = cur;
        sPrev[idx] = prev;
        if (T >= 1 && sx == 0 && idx >= 512) aSout[g] = cur;   // canonical aS_T
    }
    __syncthreads();

    const int j = sx * 256 + tid;                  // float4 column
    const float wq0 = 1.0f - sCur[2*tid];
    const float wq1 = 1.0f - sCur[2*tid + 1];
    const float bp0 = 1.0f - sPrev[2*tid];
    const float bp1 = 1.0f - sPrev[2*tid + 1];

    float c0 = 0.0f, c1 = 0.0f;

#pragma unroll 4
    for (int i = 0; i < RPB; i++) {
        const float a_c = sCur[512 + i];
        const float m1  = (T == 0) ? 0.0f : w1 * sPrev[512 + i];
        const float4 f = F[(size_t)(row0 + i) * (NN/2) + j];
        float s0 = fsig((f.y - f.x) - m1 * bp0);
        float s1 = fsig((f.w - f.z) - m1 * bp1);
        c0 += s0 * a_c;
        c1 += s1 * a_c;
        part[i * PSTR + tid] = s0 * wq0 + s1 * wq1;   // per-row partial, no shfl
        if (T == 4) {
            const float mw = w1 * a_c;
            float4 o;
            o.x = f.x + mw * wq0; o.y = f.y;
            o.z = f.z + mw * wq1; o.w = f.w;
            outF[(size_t)(row0 + i) * (NN/2) + j] = o;
        }
    }

    // c: sliced far atomics (each address: 256/NCSL = 32 contributors)
    atomicAdd(&cout[(by & (NCSL-1))*ROWS + base + 2*j],     c0);
    atomicAdd(&cout[(by & (NCSL-1))*ROWS + base + 2*j + 1], c1);

    __syncthreads();
    // r: two-stage block reduce, then exclusive plain store (sx-sliced)
    {
        const int row = tid >> 4, seg = tid & 15;
        float s = 0.0f;
#pragma unroll
        for (int u = 0; u < 16; u++) s += part[row * PSTR + seg * 16 + u];
#pragma unroll
        for (int off = 8; off > 0; off >>= 1) s += __shfl_down(s, off, 16);
        if (seg == 0) rout[sx * ROWS + row0 + row] = s;
    }
}

// Epilogue: out_S, out_C from completed r_4, c_4, aS_4, aS_3.
__global__ void kfin(const float2* __restrict__ S2, const float2* __restrict__ C2,
                     const float* __restrict__ w,
                     const float* __restrict__ rpart, const float* __restrict__ cpart,
                     const float* __restrict__ aS4, const float* __restrict__ aS3,
                     float2* __restrict__ outS, float2* __restrict__ outC)
{
    int idx = blockIdx.x * blockDim.x + threadIdx.x;
    if (idx >= ROWS) return;
    float w0 = w[0], w1 = w[1];
    float rs = rpart[0*ROWS+idx] + rpart[1*ROWS+idx]
             + rpart[2*ROWS+idx] + rpart[3*ROWS+idx];
    float cs = 0.0f;
#pragma unroll
    for (int s = 0; s < NCSL; s++) cs += cpart[s*ROWS + idx];
    float2 sv = S2[idx], cv = C2[idx];
    float qc4 = fsig(cv.x - cv.y - w0 * aS3[idx]);
    float2 os, oc;
    os.x = sv.x + w0 * qc4 + w1 * rs;
    os.y = sv.y + w1 * cs;
    oc.x = cv.x;
    oc.y = cv.y + w0 * aS4[idx];
    outS[idx] = os;
    outC[idx] = oc;
}

extern "C" void kernel_launch(void* const* d_in, const int* in_sizes, int n_in,
                              void* d_out, int out_size, void* d_ws, size_t ws_size,
                              hipStream_t stream)
{
    const float2* S2 = (const float2*)d_in[0];
    const float2* C2 = (const float2*)d_in[1];
    const float4* F4 = (const float4*)d_in[2];
    const float*  w  = (const float*)d_in[3];
    float* out = (float*)d_out;
    float* ws  = (float*)d_ws;

    // ws layout (floats)
    float* rb = ws;                              // 5 * 4*ROWS
    float* cb = ws + 5 * 4 * ROWS;               // 5 * 8*ROWS
    float* ab = ws + 5 * 4 * ROWS + 5 * 8 * ROWS; // 4 * ROWS (aS_1..aS_4)
#define RB(t) (rb + (t) * 4 * ROWS)
#define CB(t) (cb + (t) * (size_t)NCSL * ROWS)
#define AB(t) (ab + ((t) - 1) * ROWS)

    float* outS = out;
    float* outC = out + 2 * ROWS;
    float4* outF = (float4*)(out + 4 * ROWS);

    hipMemsetAsync(CB(0), 0, (size_t)NCSL * ROWS * sizeof(float), stream);

    dim3 gb(CSPLIT, NBY), bb(256);
    kbig<0><<<gb, bb, 0, stream>>>(F4, S2, C2, w, nullptr, nullptr, nullptr, nullptr,
                                   RB(0), CB(0), CB(1), nullptr, nullptr);
    kbig<1><<<gb, bb, 0, stream>>>(F4, S2, C2, w, RB(0), CB(0), nullptr, nullptr,
                                   RB(1), CB(1), CB(2), AB(1), nullptr);
    kbig<2><<<gb, bb, 0, stream>>>(F4, S2, C2, w, RB(1), CB(1), AB(1), nullptr,
                                   RB(2), CB(2), CB(3), AB(2), nullptr);
    kbig<3><<<gb, bb, 0, stream>>>(F4, S2, C2, w, RB(2), CB(2), AB(2), AB(1),
                                   RB(3), CB(3), CB(4), AB(3), nullptr);
    kbig<4><<<gb, bb, 0, stream>>>(F4, S2, C2, w, RB(3), CB(3), AB(3), AB(2),
                                   RB(4), CB(4), nullptr, AB(4), outF);
    kfin<<<dim3(ROWS/256), bb, 0, stream>>>(S2, C2, w, RB(4), CB(4), AB(4), AB(3),
                                            (float2*)outS, (float2*)outC);
}